// Round 1
// baseline (285.993 us; speedup 1.0000x reference)
//
#include <hip/hip_runtime.h>
#include <stdint.h>

#define HH 2048
#define WW 2048
#define HW (HH * WW)
#define SROWS 16

// ws layout (uint32 index):
// [0] minbits, [1] maxbits, [2..257] hist (uint), [258..513] cdf (float), [514..519] acc (float)
// acc: 0=recon_low_sum, 1=recon_eq_sum, 2=sum|dRg|, 3=sumRg, 4=sum|dL|exp(-10|dRg|), 5=sum L*exp(-10Rg)

__device__ __forceinline__ float gray_pil(float r, float g, float b) {
    float qr = floorf(fminf(fmaxf(r, 0.f), 1.f) * 255.f);
    float qg = floorf(fminf(fmaxf(g, 0.f), 1.f) * 255.f);
    float qb = floorf(fminf(fmaxf(b, 0.f), 1.f) * 255.f);
    // all terms are integers < 2^24: exact in fp32
    float s = floorf((qr * 19595.f + qg * 38470.f + qb * 7471.f + 32768.f) * (1.f / 65536.f));
    return s * (1.f / 255.f);
}

__global__ void init_k(uint32_t* ctl) {
    int t = threadIdx.x;
    if (t < 256) ctl[2 + t] = 0u;
    if (t < 6) ((float*)ctl)[514 + t] = 0.f;
    if (t == 0) { ctl[0] = 0x7F800000u; ctl[1] = 0u; }
}

__global__ __launch_bounds__(256) void minmax_k(const float* __restrict__ im, uint32_t* ctl) {
    int idx = blockIdx.x * blockDim.x + threadIdx.x;
    int stride = gridDim.x * blockDim.x;
    float vmin = __uint_as_float(0x7F800000u), vmax = 0.f;
    for (; idx < HW; idx += stride) {
        float m = fmaxf(im[idx], fmaxf(im[idx + HW], im[idx + 2 * HW]));
        vmin = fminf(vmin, m);
        vmax = fmaxf(vmax, m);
    }
    for (int off = 32; off; off >>= 1) {
        vmin = fminf(vmin, __shfl_down(vmin, off));
        vmax = fmaxf(vmax, __shfl_down(vmax, off));
    }
    __shared__ float smin[4], smax[4];
    int lane = threadIdx.x & 63, wv = threadIdx.x >> 6;
    if (lane == 0) { smin[wv] = vmin; smax[wv] = vmax; }
    __syncthreads();
    if (threadIdx.x == 0) {
        float m = smin[0], M = smax[0];
        for (int i = 1; i < 4; i++) { m = fminf(m, smin[i]); M = fmaxf(M, smax[i]); }
        atomicMin(&ctl[0], __float_as_uint(m));  // values >= 0: uint order == float order
        atomicMax(&ctl[1], __float_as_uint(M));
    }
}

__global__ __launch_bounds__(256) void hist_k(const float* __restrict__ im, uint32_t* ctl) {
    __shared__ uint32_t lh[256];
    for (int i = threadIdx.x; i < 256; i += blockDim.x) lh[i] = 0u;
    __syncthreads();
    float vmin = __uint_as_float(ctl[0]);
    float vmax = __uint_as_float(ctl[1]);
    float scale = 256.0f / (vmax - vmin);
    int idx = blockIdx.x * blockDim.x + threadIdx.x;
    int stride = gridDim.x * blockDim.x;
    for (; idx < HW; idx += stride) {
        float m = fmaxf(im[idx], fmaxf(im[idx + HW], im[idx + 2 * HW]));
        int b = (int)((m - vmin) * scale);
        b = b < 0 ? 0 : (b > 255 ? 255 : b);
        atomicAdd(&lh[b], 1u);
    }
    __syncthreads();
    for (int i = threadIdx.x; i < 256; i += blockDim.x)
        if (lh[i]) atomicAdd(&ctl[2 + i], lh[i]);
}

__global__ void cdf_k(uint32_t* ctl) {
    if (threadIdx.x == 0 && blockIdx.x == 0) {
        float* cdf = (float*)(ctl + 258);
        unsigned long long c = 0;
        for (int i = 0; i < 256; i++) {
            c += ctl[2 + i];
            cdf[i] = (float)((double)c / (double)HW);
        }
    }
}

__global__ __launch_bounds__(256) void main_k(const float* __restrict__ im,
                                              const float* __restrict__ R,
                                              const float* __restrict__ L,
                                              uint32_t* ctl) {
    __shared__ float scdf[256];
    __shared__ float red[6][4];
    for (int i = threadIdx.x; i < 256; i += blockDim.x)
        scdf[i] = ((const float*)(ctl + 258))[i];
    float vmin = __uint_as_float(ctl[0]);
    float vmax = __uint_as_float(ctl[1]);
    float inv_dw = 256.0f / (vmax - vmin);
    __syncthreads();

    int w = blockIdx.x * blockDim.x + threadIdx.x;  // column
    int h0 = blockIdx.y * SROWS;

    float a0 = 0.f, a1 = 0.f, a2 = 0.f, a3 = 0.f, a4 = 0.f, a5 = 0.f;
    float rg_prev = 0.f, l_prev = 0.f;  // zero-pad above row 0 (boundary term h=0)
    if (h0 > 0) {
        int p = (h0 - 1) * WW + w;
        rg_prev = gray_pil(R[p], R[p + HW], R[p + 2 * HW]);
        l_prev = L[p];
    }
    for (int h = h0; h < h0 + SROWS; ++h) {
        int p = h * WW + w;
        float r0 = R[p], r1 = R[p + HW], r2 = R[p + 2 * HW];
        float i0 = im[p], i1 = im[p + HW], i2 = im[p + 2 * HW];
        float l = L[p];
        a0 += fabsf(r0 * l - i0) + fabsf(r1 * l - i1) + fabsf(r2 * l - i2);
        float rmax = fmaxf(r0, fmaxf(r1, r2));
        float imax = fmaxf(i0, fmaxf(i1, i2));
        // interp(imax, edges[:-1], cdf): uniform grid
        float t = (imax - vmin) * inv_dw;  // >= 0 since imax >= vmin
        int bi = (int)t;
        float eq;
        if (bi >= 255) eq = scdf[255];
        else {
            float fr = t - (float)bi;
            eq = scdf[bi] + fr * (scdf[bi + 1] - scdf[bi]);
        }
        a1 += fabsf(rmax - eq);
        float rg = gray_pil(r0, r1, r2);
        a3 += rg;
        a5 += l * __expf(-10.f * rg);
        float drg = fabsf(rg - rg_prev);
        float dl = fabsf(l - l_prev);
        a2 += drg;
        a4 += dl * __expf(-10.f * drg);
        rg_prev = rg;
        l_prev = l;
    }
    if (h0 + SROWS == HH) {  // boundary term at h = 2048: |0 - x[2047]|
        a2 += rg_prev;
        a4 += l_prev * __expf(-10.f * rg_prev);
    }

    // block reduction: wave shfl -> LDS -> thread 0 atomics
    for (int off = 32; off; off >>= 1) {
        a0 += __shfl_down(a0, off);
        a1 += __shfl_down(a1, off);
        a2 += __shfl_down(a2, off);
        a3 += __shfl_down(a3, off);
        a4 += __shfl_down(a4, off);
        a5 += __shfl_down(a5, off);
    }
    int lane = threadIdx.x & 63, wv = threadIdx.x >> 6;
    if (lane == 0) {
        red[0][wv] = a0; red[1][wv] = a1; red[2][wv] = a2;
        red[3][wv] = a3; red[4][wv] = a4; red[5][wv] = a5;
    }
    __syncthreads();
    if (threadIdx.x == 0) {
        float s0 = 0, s1 = 0, s2 = 0, s3 = 0, s4 = 0, s5 = 0;
        for (int i = 0; i < 4; i++) {
            s0 += red[0][i]; s1 += red[1][i]; s2 += red[2][i];
            s3 += red[3][i]; s4 += red[4][i]; s5 += red[5][i];
        }
        float* acc = (float*)(ctl + 514);
        atomicAdd(&acc[0], s0);
        atomicAdd(&acc[1], s1);
        atomicAdd(&acc[2], s2);
        atomicAdd(&acc[3], s3);
        atomicAdd(&acc[4], s4);
        atomicAdd(&acc[5], s5);
    }
}

__global__ void final_k(const uint32_t* ctl, float* out) {
    if (threadIdx.x == 0 && blockIdx.x == 0) {
        const float* acc = (const float*)(ctl + 514);
        float recon_low = acc[0] / (3.0f * (float)HW);
        float recon_eq = acc[1] / (float)HW;
        float denom = 2.0f * 2049.0f * 2050.0f;
        float r_smooth = (acc[2] + 2.f * acc[3]) / denom;
        float ismooth = (acc[4] + 2.f * acc[5]) / denom;
        out[0] = recon_low + 0.1f * ismooth + 0.1f * recon_eq + 0.01f * r_smooth;
    }
}

extern "C" void kernel_launch(void* const* d_in, const int* in_sizes, int n_in,
                              void* d_out, int out_size, void* d_ws, size_t ws_size,
                              hipStream_t stream) {
    const float* im = (const float*)d_in[0];
    const float* R = (const float*)d_in[1];
    const float* L = (const float*)d_in[2];
    float* out = (float*)d_out;
    uint32_t* ctl = (uint32_t*)d_ws;

    hipLaunchKernelGGL(init_k, dim3(1), dim3(256), 0, stream, ctl);
    hipLaunchKernelGGL(minmax_k, dim3(1024), dim3(256), 0, stream, im, ctl);
    hipLaunchKernelGGL(hist_k, dim3(1024), dim3(256), 0, stream, im, ctl);
    hipLaunchKernelGGL(cdf_k, dim3(1), dim3(64), 0, stream, ctl);
    hipLaunchKernelGGL(main_k, dim3(WW / 256, HH / SROWS), dim3(256), 0, stream,
                       im, R, L, ctl);
    hipLaunchKernelGGL(final_k, dim3(1), dim3(64), 0, stream, ctl, out);
}

// Round 2
// 242.118 us; speedup vs baseline: 1.1812x; 1.1812x over previous
//
#include <hip/hip_runtime.h>
#include <stdint.h>

#define HH 2048
#define WW 2048
#define HW (HH * WW)
#define SROWS 8

// ws layout (uint32 index):
// [0] minbits, [1] maxbits, [2..257] hist (uint), [258..513] cdf (float), [514..519] acc (float)

__device__ __forceinline__ float gray_pil(float r, float g, float b) {
    float qr = floorf(fminf(fmaxf(r, 0.f), 1.f) * 255.f);
    float qg = floorf(fminf(fmaxf(g, 0.f), 1.f) * 255.f);
    float qb = floorf(fminf(fmaxf(b, 0.f), 1.f) * 255.f);
    // all terms are integers < 2^24: exact in fp32
    float s = floorf((qr * 19595.f + qg * 38470.f + qb * 7471.f + 32768.f) * (1.f / 65536.f));
    return s * (1.f / 255.f);
}

__global__ void init_k(uint32_t* ctl) {
    int t = threadIdx.x;
    if (t < 256) ctl[2 + t] = 0u;
    if (t < 6) ((float*)ctl)[514 + t] = 0.f;
    if (t == 0) { ctl[0] = 0x7F800000u; ctl[1] = 0u; }
}

__global__ __launch_bounds__(256) void minmax_k(const float* __restrict__ im, uint32_t* ctl) {
    const int N4 = HW / 4;
    int idx = blockIdx.x * blockDim.x + threadIdx.x;
    int stride = gridDim.x * blockDim.x;
    const float4* im4 = (const float4*)im;
    float vmin = __uint_as_float(0x7F800000u), vmax = 0.f;
    for (; idx < N4; idx += stride) {
        float4 a = im4[idx], b = im4[idx + N4], c = im4[idx + 2 * N4];
        float m0 = fmaxf(a.x, fmaxf(b.x, c.x));
        float m1 = fmaxf(a.y, fmaxf(b.y, c.y));
        float m2 = fmaxf(a.z, fmaxf(b.z, c.z));
        float m3 = fmaxf(a.w, fmaxf(b.w, c.w));
        vmin = fminf(vmin, fminf(fminf(m0, m1), fminf(m2, m3)));
        vmax = fmaxf(vmax, fmaxf(fmaxf(m0, m1), fmaxf(m2, m3)));
    }
    for (int off = 32; off; off >>= 1) {
        vmin = fminf(vmin, __shfl_down(vmin, off));
        vmax = fmaxf(vmax, __shfl_down(vmax, off));
    }
    __shared__ float smin[4], smax[4];
    int lane = threadIdx.x & 63, wv = threadIdx.x >> 6;
    if (lane == 0) { smin[wv] = vmin; smax[wv] = vmax; }
    __syncthreads();
    if (threadIdx.x == 0) {
        float m = smin[0], M = smax[0];
        for (int i = 1; i < 4; i++) { m = fminf(m, smin[i]); M = fmaxf(M, smax[i]); }
        atomicMin(&ctl[0], __float_as_uint(m));  // values >= 0: uint order == float order
        atomicMax(&ctl[1], __float_as_uint(M));
    }
}

__global__ __launch_bounds__(256) void hist_k(const float* __restrict__ im, uint32_t* ctl) {
    __shared__ uint32_t lh[256];
    for (int i = threadIdx.x; i < 256; i += blockDim.x) lh[i] = 0u;
    __syncthreads();
    float vmin = __uint_as_float(ctl[0]);
    float vmax = __uint_as_float(ctl[1]);
    float scale = 256.0f / (vmax - vmin);
    const int N4 = HW / 4;
    int idx = blockIdx.x * blockDim.x + threadIdx.x;
    int stride = gridDim.x * blockDim.x;
    const float4* im4 = (const float4*)im;
    for (; idx < N4; idx += stride) {
        float4 a = im4[idx], b = im4[idx + N4], c = im4[idx + 2 * N4];
        float m[4];
        m[0] = fmaxf(a.x, fmaxf(b.x, c.x));
        m[1] = fmaxf(a.y, fmaxf(b.y, c.y));
        m[2] = fmaxf(a.z, fmaxf(b.z, c.z));
        m[3] = fmaxf(a.w, fmaxf(b.w, c.w));
#pragma unroll
        for (int j = 0; j < 4; ++j) {
            int bin = (int)((m[j] - vmin) * scale);
            bin = bin < 0 ? 0 : (bin > 255 ? 255 : bin);
            atomicAdd(&lh[bin], 1u);
        }
    }
    __syncthreads();
    for (int i = threadIdx.x; i < 256; i += blockDim.x)
        if (lh[i]) atomicAdd(&ctl[2 + i], lh[i]);
}

__global__ void cdf_k(uint32_t* ctl) {
    if (threadIdx.x == 0 && blockIdx.x == 0) {
        float* cdf = (float*)(ctl + 258);
        unsigned long long c = 0;
        for (int i = 0; i < 256; i++) {
            c += ctl[2 + i];
            cdf[i] = (float)((double)c / (double)HW);
        }
    }
}

__global__ __launch_bounds__(256) void main_k(const float* __restrict__ im,
                                              const float* __restrict__ R,
                                              const float* __restrict__ L,
                                              uint32_t* ctl) {
    __shared__ float scdf[256];
    __shared__ float red[6][4];
    for (int i = threadIdx.x; i < 256; i += 256)
        scdf[i] = ((const float*)(ctl + 258))[i];
    float vmin = __uint_as_float(ctl[0]);
    float vmax = __uint_as_float(ctl[1]);
    float inv_dw = 256.0f / (vmax - vmin);
    __syncthreads();

    int w = (blockIdx.x * 256 + threadIdx.x) * 4;  // 4 adjacent columns per thread
    int h0 = blockIdx.y * SROWS;

    float a0 = 0.f, a1 = 0.f, a2 = 0.f, a3 = 0.f, a4 = 0.f, a5 = 0.f;
    float rgp[4], lp[4];
    if (h0 > 0) {
        int p = (h0 - 1) * WW + w;
        float4 R0 = *(const float4*)(R + p);
        float4 R1 = *(const float4*)(R + p + HW);
        float4 R2 = *(const float4*)(R + p + 2 * HW);
        float4 Lv = *(const float4*)(L + p);
        float r0[4] = {R0.x, R0.y, R0.z, R0.w};
        float r1[4] = {R1.x, R1.y, R1.z, R1.w};
        float r2[4] = {R2.x, R2.y, R2.z, R2.w};
        float lv[4] = {Lv.x, Lv.y, Lv.z, Lv.w};
#pragma unroll
        for (int j = 0; j < 4; ++j) {
            rgp[j] = gray_pil(r0[j], r1[j], r2[j]);
            lp[j] = lv[j];
        }
    } else {
#pragma unroll
        for (int j = 0; j < 4; ++j) { rgp[j] = 0.f; lp[j] = 0.f; }
    }

#pragma unroll 2
    for (int h = h0; h < h0 + SROWS; ++h) {
        int p = h * WW + w;
        float4 R0 = *(const float4*)(R + p);
        float4 R1 = *(const float4*)(R + p + HW);
        float4 R2 = *(const float4*)(R + p + 2 * HW);
        float4 I0 = *(const float4*)(im + p);
        float4 I1 = *(const float4*)(im + p + HW);
        float4 I2 = *(const float4*)(im + p + 2 * HW);
        float4 Lv = *(const float4*)(L + p);
        float r0[4] = {R0.x, R0.y, R0.z, R0.w};
        float r1[4] = {R1.x, R1.y, R1.z, R1.w};
        float r2[4] = {R2.x, R2.y, R2.z, R2.w};
        float i0[4] = {I0.x, I0.y, I0.z, I0.w};
        float i1[4] = {I1.x, I1.y, I1.z, I1.w};
        float i2[4] = {I2.x, I2.y, I2.z, I2.w};
        float lv[4] = {Lv.x, Lv.y, Lv.z, Lv.w};
#pragma unroll
        for (int j = 0; j < 4; ++j) {
            float l = lv[j];
            a0 += fabsf(r0[j] * l - i0[j]) + fabsf(r1[j] * l - i1[j]) + fabsf(r2[j] * l - i2[j]);
            float rmax = fmaxf(r0[j], fmaxf(r1[j], r2[j]));
            float imax = fmaxf(i0[j], fmaxf(i1[j], i2[j]));
            // interp(imax, edges[:-1], cdf) on uniform grid
            float t = (imax - vmin) * inv_dw;
            int bi = (int)t;
            float eq;
            if (bi >= 255) eq = scdf[255];
            else {
                float fr = t - (float)bi;
                eq = scdf[bi] + fr * (scdf[bi + 1] - scdf[bi]);
            }
            a1 += fabsf(rmax - eq);
            float rg = gray_pil(r0[j], r1[j], r2[j]);
            a3 += rg;
            a5 += l * __expf(-10.f * rg);
            float drg = fabsf(rg - rgp[j]);
            float dl = fabsf(l - lp[j]);
            a2 += drg;
            a4 += dl * __expf(-10.f * drg);
            rgp[j] = rg;
            lp[j] = l;
        }
    }
    if (h0 + SROWS == HH) {  // boundary at h = 2048: |0 - x[2047]|
#pragma unroll
        for (int j = 0; j < 4; ++j) {
            a2 += rgp[j];
            a4 += lp[j] * __expf(-10.f * rgp[j]);
        }
    }

    for (int off = 32; off; off >>= 1) {
        a0 += __shfl_down(a0, off);
        a1 += __shfl_down(a1, off);
        a2 += __shfl_down(a2, off);
        a3 += __shfl_down(a3, off);
        a4 += __shfl_down(a4, off);
        a5 += __shfl_down(a5, off);
    }
    int lane = threadIdx.x & 63, wv = threadIdx.x >> 6;
    if (lane == 0) {
        red[0][wv] = a0; red[1][wv] = a1; red[2][wv] = a2;
        red[3][wv] = a3; red[4][wv] = a4; red[5][wv] = a5;
    }
    __syncthreads();
    if (threadIdx.x == 0) {
        float s0 = 0, s1 = 0, s2 = 0, s3 = 0, s4 = 0, s5 = 0;
        for (int i = 0; i < 4; i++) {
            s0 += red[0][i]; s1 += red[1][i]; s2 += red[2][i];
            s3 += red[3][i]; s4 += red[4][i]; s5 += red[5][i];
        }
        float* acc = (float*)(ctl + 514);
        atomicAdd(&acc[0], s0);
        atomicAdd(&acc[1], s1);
        atomicAdd(&acc[2], s2);
        atomicAdd(&acc[3], s3);
        atomicAdd(&acc[4], s4);
        atomicAdd(&acc[5], s5);
    }
}

__global__ void final_k(const uint32_t* ctl, float* out) {
    if (threadIdx.x == 0 && blockIdx.x == 0) {
        const float* acc = (const float*)(ctl + 514);
        float recon_low = acc[0] / (3.0f * (float)HW);
        float recon_eq = acc[1] / (float)HW;
        float denom = 2.0f * 2049.0f * 2050.0f;
        float r_smooth = (acc[2] + 2.f * acc[3]) / denom;
        float ismooth = (acc[4] + 2.f * acc[5]) / denom;
        out[0] = recon_low + 0.1f * ismooth + 0.1f * recon_eq + 0.01f * r_smooth;
    }
}

extern "C" void kernel_launch(void* const* d_in, const int* in_sizes, int n_in,
                              void* d_out, int out_size, void* d_ws, size_t ws_size,
                              hipStream_t stream) {
    const float* im = (const float*)d_in[0];
    const float* R = (const float*)d_in[1];
    const float* L = (const float*)d_in[2];
    float* out = (float*)d_out;
    uint32_t* ctl = (uint32_t*)d_ws;

    hipLaunchKernelGGL(init_k, dim3(1), dim3(256), 0, stream, ctl);
    hipLaunchKernelGGL(minmax_k, dim3(1024), dim3(256), 0, stream, im, ctl);
    hipLaunchKernelGGL(hist_k, dim3(1024), dim3(256), 0, stream, im, ctl);
    hipLaunchKernelGGL(cdf_k, dim3(1), dim3(64), 0, stream, ctl);
    hipLaunchKernelGGL(main_k, dim3(WW / 4 / 256, HH / SROWS), dim3(256), 0, stream,
                       im, R, L, ctl);
    hipLaunchKernelGGL(final_k, dim3(1), dim3(64), 0, stream, ctl, out);
}